// Round 5
// baseline (490.380 us; speedup 1.0000x reference)
//
#include <hip/hip_runtime.h>

#define NEG_SLOPE 0.01f
#define ETA 0.5f
#define SCAN_CHUNK 512  // elements per scan block (256 threads x 2)
#define NEG_BIG -3.402823466e38f

// af/bf node dots + zero the histogram (replaces the memset dispatch).
__global__ void k_prep(const float* __restrict__ h, const float* __restrict__ whw,
                       float* __restrict__ af, float* __restrict__ bf,
                       int* __restrict__ cnt, int n) {
  int gid = blockIdx.x * blockDim.x + threadIdx.x;
  int node = gid >> 4, lane = gid & 15;
  if (node >= n) return;
  float4 x  = ((const float4*)(h + (size_t)node * 64))[lane];
  float4 wa = ((const float4*)whw)[lane];
  float4 wb = ((const float4*)(whw + 64))[lane];
  float pa = x.x * wa.x + x.y * wa.y + x.z * wa.z + x.w * wa.w;
  float pb = x.x * wb.x + x.y * wb.y + x.z * wb.z + x.w * wb.w;
#pragma unroll
  for (int o = 8; o; o >>= 1) {
    pa += __shfl_xor(pa, o);
    pb += __shfl_xor(pb, o);
  }
  if (lane == 0) { af[node] = pa; bf[node] = pb; cnt[node] = 0; }
}

// Histogram of dst.
__global__ void k_hist(const int* __restrict__ dst, int* __restrict__ cnt, int ne) {
  int e = blockIdx.x * blockDim.x + threadIdx.x;
  if (e >= ne) return;
  atomicAdd(cnt + dst[e], 1);
}

// Scan stage 1: per-block totals over SCAN_CHUNK elements.
__global__ void k_scan1(const int* __restrict__ cnt, int* __restrict__ bsum, int n) {
  __shared__ int sh[256];
  int t = threadIdx.x;
  int base = blockIdx.x * SCAN_CHUNK;
  int i0 = base + t, i1 = base + 256 + t;
  int v = (i0 < n ? cnt[i0] : 0) + (i1 < n ? cnt[i1] : 0);
  sh[t] = v;
  __syncthreads();
  for (int s = 128; s; s >>= 1) {
    if (t < s) sh[t] += sh[t + s];
    __syncthreads();
  }
  if (t == 0) bsum[blockIdx.x] = sh[0];
}

// Scan stage 2: single-block exclusive scan of block sums (B <= 256).
__global__ void k_scan2(int* __restrict__ bsum, int* __restrict__ off, int B, int n, int ne) {
  __shared__ int sh[256];
  int t = threadIdx.x;
  int v = (t < B) ? bsum[t] : 0;
  sh[t] = v;
  __syncthreads();
  for (int s = 1; s < 256; s <<= 1) {
    int a = (t >= s) ? sh[t - s] : 0;
    __syncthreads();
    sh[t] += a;
    __syncthreads();
  }
  if (t < B) bsum[t] = sh[t] - v;  // exclusive
  if (t == 0) off[n] = ne;
}

// Scan stage 3: per-block exclusive scan + block base -> off[i].
__global__ void k_scan3(const int* __restrict__ cnt, const int* __restrict__ bbase,
                        int* __restrict__ off, int n) {
  __shared__ int sh[256];
  int t = threadIdx.x;
  int base = blockIdx.x * SCAN_CHUNK;
  int i0 = base + 2 * t, i1 = i0 + 1;
  int a0 = (i0 < n) ? cnt[i0] : 0;
  int a1 = (i1 < n) ? cnt[i1] : 0;
  int tsum = a0 + a1;
  sh[t] = tsum;
  __syncthreads();
  for (int s = 1; s < 256; s <<= 1) {
    int a = (t >= s) ? sh[t - s] : 0;
    __syncthreads();
    sh[t] += a;
    __syncthreads();
  }
  int excl = sh[t] - tsum + bbase[blockIdx.x];
  if (i0 < n) off[i0] = excl;
  if (i1 < n) off[i1] = excl + a0;
}

// Bucket edges by dst, destructively bumping off: after this kernel,
// off[d] == original off[d+1]; k_fused reads [off[d-1], off[d]).
__global__ void k_bucket(const int* __restrict__ src, const int* __restrict__ dst,
                         int* __restrict__ off, int* __restrict__ srcs, int ne) {
  int e = blockIdx.x * blockDim.x + threadIdx.x;
  if (e >= ne) return;
  int d = dst[e];
  int slot = atomicAdd(off + d, 1);
  srcs[slot] = src[e];
}

// One wave per dst node, 8 edges in flight (8 lanes x 2 float4 each).
// f-stream: no-max softmax (wf bounded ~7.5). t-stream: online max
// (self-loops give ||tax||^2 up to ~120 -> needs max subtraction).
__global__ void k_fused(const float* __restrict__ h, const float* __restrict__ tax,
                        const float* __restrict__ af, const float* __restrict__ bf,
                        const int* __restrict__ off, const int* __restrict__ srcs,
                        float* __restrict__ z, int n) {
  int wave = (blockIdx.x * blockDim.x + threadIdx.x) >> 6;
  if (wave >= n) return;
  int lane = threadIdx.x & 63;
  int g = lane >> 3, q = lane & 7;  // group = edge slot, q = feature octet
  int d = wave;
  int beg = d ? off[d - 1] : 0;
  int end = off[d];
  const float4* tdp = (const float4*)(tax + (size_t)d * 64 + q * 8);
  float4 td0 = tdp[0], td1 = tdp[1];
  float bfd = bf[d];
  float sf = 0.f;
  float4 zf0 = make_float4(0.f, 0.f, 0.f, 0.f), zf1 = make_float4(0.f, 0.f, 0.f, 0.f);
  float mt = NEG_BIG, st = 0.f;  // NEG_BIG (not -inf): empty merge stays finite
  float4 zt0 = make_float4(0.f, 0.f, 0.f, 0.f), zt1 = make_float4(0.f, 0.f, 0.f, 0.f);
  for (int i = beg + g; i < end; i += 8) {
    int s = srcs[i];
    const float4* tsp = (const float4*)(tax + (size_t)s * 64 + q * 8);
    const float4* hvp = (const float4*)(h + (size_t)s * 64 + q * 8);
    float4 ts0 = tsp[0], ts1 = tsp[1];
    float4 hv0 = hvp[0], hv1 = hvp[1];
    float p = ts0.x * td0.x + ts0.y * td0.y + ts0.z * td0.z + ts0.w * td0.w
            + ts1.x * td1.x + ts1.y * td1.y + ts1.z * td1.z + ts1.w * td1.w;
    p += __shfl_xor(p, 1);
    p += __shfl_xor(p, 2);
    p += __shfl_xor(p, 4);
    float wf = af[s] + bfd;
    wf = (wf > 0.f) ? wf : NEG_SLOPE * wf;
    float ef = __expf(wf);
    sf += ef;
    zf0.x += ef * hv0.x; zf0.y += ef * hv0.y; zf0.z += ef * hv0.z; zf0.w += ef * hv0.w;
    zf1.x += ef * hv1.x; zf1.y += ef * hv1.y; zf1.z += ef * hv1.z; zf1.w += ef * hv1.w;
    float nm = fmaxf(mt, p);
    float sc = __expf(mt - nm);
    float et = __expf(p - nm);
    st = st * sc + et;
    zt0.x = zt0.x * sc + et * hv0.x; zt0.y = zt0.y * sc + et * hv0.y;
    zt0.z = zt0.z * sc + et * hv0.z; zt0.w = zt0.w * sc + et * hv0.w;
    zt1.x = zt1.x * sc + et * hv1.x; zt1.y = zt1.y * sc + et * hv1.y;
    zt1.z = zt1.z * sc + et * hv1.z; zt1.w = zt1.w * sc + et * hv1.w;
    mt = nm;
  }
  // Combine the 8 edge-groups (butterfly over the group bits).
#pragma unroll
  for (int o = 8; o < 64; o <<= 1) {
    sf += __shfl_xor(sf, o);
    zf0.x += __shfl_xor(zf0.x, o); zf0.y += __shfl_xor(zf0.y, o);
    zf0.z += __shfl_xor(zf0.z, o); zf0.w += __shfl_xor(zf0.w, o);
    zf1.x += __shfl_xor(zf1.x, o); zf1.y += __shfl_xor(zf1.y, o);
    zf1.z += __shfl_xor(zf1.z, o); zf1.w += __shfl_xor(zf1.w, o);
    float mo = __shfl_xor(mt, o);
    float so = __shfl_xor(st, o);
    float a0x = __shfl_xor(zt0.x, o), a0y = __shfl_xor(zt0.y, o);
    float a0z = __shfl_xor(zt0.z, o), a0w = __shfl_xor(zt0.w, o);
    float a1x = __shfl_xor(zt1.x, o), a1y = __shfl_xor(zt1.y, o);
    float a1z = __shfl_xor(zt1.z, o), a1w = __shfl_xor(zt1.w, o);
    float nm = fmaxf(mt, mo);
    float a = __expf(mt - nm);
    float b = __expf(mo - nm);
    st = st * a + so * b;
    zt0.x = zt0.x * a + a0x * b; zt0.y = zt0.y * a + a0y * b;
    zt0.z = zt0.z * a + a0z * b; zt0.w = zt0.w * a + a0w * b;
    zt1.x = zt1.x * a + a1x * b; zt1.y = zt1.y * a + a1y * b;
    zt1.z = zt1.z * a + a1z * b; zt1.w = zt1.w * a + a1w * b;
    mt = nm;
  }
  if (g == 0) {
    float4 o0 = make_float4(0.f, 0.f, 0.f, 0.f), o1 = make_float4(0.f, 0.f, 0.f, 0.f);
    if (end > beg) {
      float rf = ETA / sf, rt = (1.f - ETA) / st;
      o0.x = rf * zf0.x + rt * zt0.x; o0.y = rf * zf0.y + rt * zt0.y;
      o0.z = rf * zf0.z + rt * zt0.z; o0.w = rf * zf0.w + rt * zt0.w;
      o1.x = rf * zf1.x + rt * zt1.x; o1.y = rf * zf1.y + rt * zt1.y;
      o1.z = rf * zf1.z + rt * zt1.z; o1.w = rf * zf1.w + rt * zt1.w;
    }
    float4* zp = (float4*)(z + (size_t)d * 64 + q * 8);
    zp[0] = o0;
    zp[1] = o1;
  }
}

// out[n][j] = sum_k z[n][k] * W[j][k] + b[j].
__launch_bounds__(256)
__global__ void k_out_gemm(const float* __restrict__ z, const float* __restrict__ W,
                           const float* __restrict__ b, float* __restrict__ out, int n) {
  int t = threadIdx.x;
  int j = t & 63, nl = t >> 6;
  float wreg[64];
#pragma unroll
  for (int i = 0; i < 16; ++i)
    ((float4*)wreg)[i] = ((const float4*)(W + (size_t)j * 64))[i];
  float bias = b[j];
  int stride = gridDim.x * 4;
  for (int node = blockIdx.x * 4 + nl; node < n; node += stride) {
    float zv = z[(size_t)node * 64 + j];
    float acc = bias;
#pragma unroll
    for (int k = 0; k < 64; ++k)
      acc += __shfl(zv, k) * wreg[k];
    out[(size_t)node * 64 + j] = acc;
  }
}

extern "C" void kernel_launch(void* const* d_in, const int* in_sizes, int n_in,
                              void* d_out, int out_size, void* d_ws, size_t ws_size,
                              hipStream_t stream) {
  const float* h   = (const float*)d_in[0];
  const float* tax = (const float*)d_in[1];
  const int*   src = (const int*)d_in[2];
  const int*   dst = (const int*)d_in[3];
  const float* whw = (const float*)d_in[4];
  const float* Ww  = (const float*)d_in[5];
  const float* Wb  = (const float*)d_in[6];
  float* out = (float*)d_out;
  int n  = in_sizes[0] / 64;
  int ne = in_sizes[2];

  // Workspace layout (all 4-byte elements):
  float* af  = (float*)d_ws;            // n
  float* bf  = af + n;                  // n
  int*   cnt = (int*)(bf + n);          // n   (zeroed in k_prep)
  int*   off = cnt + n;                 // n+1
  int*   srcs = off + n + 1;            // ne
  float* z   = (float*)(srcs + ne);     // n*64
  int*   bsum = (int*)(z + (size_t)n * 64);  // scan block sums (<=256)

  int B = (n + SCAN_CHUNK - 1) / SCAN_CHUNK;

  int bn16 = (n * 16 + 255) / 256;
  int be   = (ne + 255) / 256;
  int bw   = (int)(((size_t)n * 64 + 255) / 256);

  k_prep<<<bn16, 256, 0, stream>>>(h, whw, af, bf, cnt, n);
  k_hist<<<be, 256, 0, stream>>>(dst, cnt, ne);
  k_scan1<<<B, 256, 0, stream>>>(cnt, bsum, n);
  k_scan2<<<1, 256, 0, stream>>>(bsum, off, B, n, ne);
  k_scan3<<<B, 256, 0, stream>>>(cnt, bsum, off, n);
  k_bucket<<<be, 256, 0, stream>>>(src, dst, off, srcs, ne);
  k_fused<<<bw, 256, 0, stream>>>(h, tax, af, bf, off, srcs, z, n);
  k_out_gemm<<<1024, 256, 0, stream>>>(z, Ww, Wb, out, n);
}

// Round 6
// 349.913 us; speedup vs baseline: 1.4014x; 1.4014x over previous
//
#include <hip/hip_runtime.h>

#define NEG_SLOPE 0.01f
#define ETA 0.5f
#define NEG_BIG -3.402823466e38f
#define PCHUNK 4096   // edges per k_partition block
#define CAP 10240     // per-coarse-bucket region capacity (mean 8192 + 22 sigma)

// af/bf node dots + zero the 256 coarse-bucket cursors.
__global__ void k_prep(const float* __restrict__ h, const float* __restrict__ whw,
                       float* __restrict__ af, float* __restrict__ bf,
                       int* __restrict__ gcur, int n) {
  int gid = blockIdx.x * blockDim.x + threadIdx.x;
  if (gid < 256) gcur[gid] = 0;
  int node = gid >> 4, lane = gid & 15;
  if (node >= n) return;
  float4 x  = ((const float4*)(h + (size_t)node * 64))[lane];
  float4 wa = ((const float4*)whw)[lane];
  float4 wb = ((const float4*)(whw + 64))[lane];
  float pa = x.x * wa.x + x.y * wa.y + x.z * wa.z + x.w * wa.w;
  float pb = x.x * wb.x + x.y * wb.y + x.z * wb.z + x.w * wb.w;
#pragma unroll
  for (int o = 8; o; o >>= 1) {
    pa += __shfl_xor(pa, o);
    pb += __shfl_xor(pb, o);
  }
  if (lane == 0) { af[node] = pa; bf[node] = pb; }
}

// Coarse partition: block-local counting sort by bucket = dst>>9, one global
// atomic reservation per (block,bucket), coalesced run copy-out into
// fixed-CAP bucket regions (psrc/pdst planes).
__global__ void k_partition(const int* __restrict__ src, const int* __restrict__ dst,
                            int* __restrict__ gcur,
                            int* __restrict__ psrc, int* __restrict__ pdst, int ne) {
  __shared__ int s_hist[256];
  __shared__ int s_scan[256];
  __shared__ int s_res[256];
  __shared__ int s_srcb[PCHUNK];
  __shared__ int s_dstb[PCHUNK];
  int t = threadIdx.x;
  int base = blockIdx.x * PCHUNK;
  int cnt = ne - base; if (cnt > PCHUNK) cnt = PCHUNK;
  s_hist[t] = 0;
  __syncthreads();
  for (int i = t; i < cnt; i += 256)
    atomicAdd(&s_hist[dst[base + i] >> 9], 1);
  __syncthreads();
  int v = s_hist[t];
  s_scan[t] = v;
  __syncthreads();
  for (int s = 1; s < 256; s <<= 1) {
    int a = (t >= s) ? s_scan[t - s] : 0;
    __syncthreads();
    s_scan[t] += a;
    __syncthreads();
  }
  int excl = s_scan[t] - v;
  if (v > 0) s_res[t] = atomicAdd(&gcur[t], v);  // region-local offset
  s_hist[t] = excl;   // cursors for rank pass
  s_scan[t] = excl;   // exclusive scan for copy-out
  __syncthreads();
  for (int i = t; i < cnt; i += 256) {
    int sd = dst[base + i];
    int pos = atomicAdd(&s_hist[sd >> 9], 1);
    s_srcb[pos] = src[base + i];
    s_dstb[pos] = sd;
  }
  __syncthreads();
  for (int i = t; i < cnt; i += 256) {
    int sd = s_dstb[i];
    int r = sd >> 9;
    int g = s_res[r] + (i - s_scan[r]);
    if (g < CAP) {  // overflow guard (statistically impossible at 22 sigma)
      int gi = r * CAP + g;
      psrc[gi] = s_srcb[i];
      pdst[gi] = sd;
    }
  }
}

// Exclusive scan of the nb coarse-bucket counts -> CSR base per bucket.
__global__ void k_cscan(const int* __restrict__ gcur, int* __restrict__ cbase,
                        int* __restrict__ off, int nb, int n, int ne) {
  __shared__ int sh[256];
  int t = threadIdx.x;
  int v = (t < nb) ? gcur[t] : 0;
  sh[t] = v;
  __syncthreads();
  for (int s = 1; s < 256; s <<= 1) {
    int a = (t >= s) ? sh[t - s] : 0;
    __syncthreads();
    sh[t] += a;
    __syncthreads();
  }
  if (t < nb) cbase[t] = sh[t] - v;
  if (t == 0) off[n] = ne;
}

// One block per coarse bucket: LDS 512-dst histogram + scan -> exact off[],
// then scatter srcs into this bucket's contiguous (L2-resident) CSR window.
__global__ void k_finesort(const int* __restrict__ psrc, const int* __restrict__ pdst,
                           const int* __restrict__ gcur, const int* __restrict__ cbase,
                           int* __restrict__ off, int* __restrict__ srcs, int n) {
  __shared__ int s_hist[512];
  __shared__ int s_scan[512];
  __shared__ int s_pair[256];
  int b = blockIdx.x;
  int t = threadIdx.x;
  int cnt = gcur[b];
  int gbase = b * CAP;
  int base = cbase[b];
  s_hist[t] = 0; s_hist[t + 256] = 0;
  __syncthreads();
  for (int i = t; i < cnt; i += 256)
    atomicAdd(&s_hist[pdst[gbase + i] & 511], 1);
  __syncthreads();
  int c0 = s_hist[2 * t], c1 = s_hist[2 * t + 1];
  int v = c0 + c1;
  s_pair[t] = v;
  __syncthreads();
  for (int s = 1; s < 256; s <<= 1) {
    int a = (t >= s) ? s_pair[t - s] : 0;
    __syncthreads();
    s_pair[t] += a;
    __syncthreads();
  }
  int pex = s_pair[t] - v;
  s_scan[2 * t] = pex;
  s_scan[2 * t + 1] = pex + c0;
  __syncthreads();
  int d0 = (b << 9) + 2 * t;
  if (d0 < n) off[d0] = base + s_scan[2 * t];
  if (d0 + 1 < n) off[d0 + 1] = base + s_scan[2 * t + 1];
  s_hist[2 * t] = s_scan[2 * t];       // cursors
  s_hist[2 * t + 1] = s_scan[2 * t + 1];
  __syncthreads();
  for (int i = t; i < cnt; i += 256) {
    int sd = pdst[gbase + i];
    int rank = atomicAdd(&s_hist[sd & 511], 1);
    srcs[base + rank] = psrc[gbase + i];
  }
}

// One wave per dst node, 4 edges in flight (16 lanes x float4 each).
// f-stream: no-max softmax (wf bounded ~7.5). t-stream: online max.
__global__ void k_fused(const float* __restrict__ h, const float* __restrict__ tax,
                        const float* __restrict__ af, const float* __restrict__ bf,
                        const int* __restrict__ off, const int* __restrict__ srcs,
                        float* __restrict__ z, int n) {
  int wave = (blockIdx.x * blockDim.x + threadIdx.x) >> 6;
  if (wave >= n) return;
  int lane = threadIdx.x & 63;
  int g = lane >> 4, q = lane & 15;
  int d = wave;
  int beg = off[d], end = off[d + 1];
  float4 td = ((const float4*)(tax + (size_t)d * 64))[q];
  float bfd = bf[d];
  float sf = 0.f;
  float4 zf = make_float4(0.f, 0.f, 0.f, 0.f);
  float mt = NEG_BIG, st = 0.f;
  float4 zt = make_float4(0.f, 0.f, 0.f, 0.f);
  for (int i = beg + g; i < end; i += 4) {
    int s = srcs[i];
    float4 ts = ((const float4*)(tax + (size_t)s * 64))[q];
    float4 hv = ((const float4*)(h + (size_t)s * 64))[q];
    float p = ts.x * td.x + ts.y * td.y + ts.z * td.z + ts.w * td.w;
    p += __shfl_xor(p, 1);
    p += __shfl_xor(p, 2);
    p += __shfl_xor(p, 4);
    p += __shfl_xor(p, 8);
    float wf = af[s] + bfd;
    wf = (wf > 0.f) ? wf : NEG_SLOPE * wf;
    float ef = __expf(wf);
    sf += ef;
    zf.x += ef * hv.x; zf.y += ef * hv.y; zf.z += ef * hv.z; zf.w += ef * hv.w;
    float nm = fmaxf(mt, p);
    float sc = __expf(mt - nm);
    float et = __expf(p - nm);
    st = st * sc + et;
    zt.x = zt.x * sc + et * hv.x;
    zt.y = zt.y * sc + et * hv.y;
    zt.z = zt.z * sc + et * hv.z;
    zt.w = zt.w * sc + et * hv.w;
    mt = nm;
  }
#pragma unroll
  for (int o = 16; o < 64; o <<= 1) {
    sf += __shfl_xor(sf, o);
    zf.x += __shfl_xor(zf.x, o); zf.y += __shfl_xor(zf.y, o);
    zf.z += __shfl_xor(zf.z, o); zf.w += __shfl_xor(zf.w, o);
    float mo  = __shfl_xor(mt, o);
    float so  = __shfl_xor(st, o);
    float zox = __shfl_xor(zt.x, o), zoy = __shfl_xor(zt.y, o);
    float zoz = __shfl_xor(zt.z, o), zow = __shfl_xor(zt.w, o);
    float nm = fmaxf(mt, mo);
    float a = __expf(mt - nm);
    float b = __expf(mo - nm);
    st = st * a + so * b;
    zt.x = zt.x * a + zox * b;
    zt.y = zt.y * a + zoy * b;
    zt.z = zt.z * a + zoz * b;
    zt.w = zt.w * a + zow * b;
    mt = nm;
  }
  if (g == 0) {
    float4 zv = make_float4(0.f, 0.f, 0.f, 0.f);
    if (end > beg) {
      float rf = ETA / sf, rt = (1.f - ETA) / st;
      zv.x = rf * zf.x + rt * zt.x;
      zv.y = rf * zf.y + rt * zt.y;
      zv.z = rf * zf.z + rt * zt.z;
      zv.w = rf * zf.w + rt * zt.w;
    }
    ((float4*)(z + (size_t)d * 64))[q] = zv;
  }
}

// out[n][j] = sum_k z[n][k] * W[j][k] + b[j].
__launch_bounds__(256)
__global__ void k_out_gemm(const float* __restrict__ z, const float* __restrict__ W,
                           const float* __restrict__ b, float* __restrict__ out, int n) {
  int t = threadIdx.x;
  int j = t & 63, nl = t >> 6;
  float wreg[64];
#pragma unroll
  for (int i = 0; i < 16; ++i)
    ((float4*)wreg)[i] = ((const float4*)(W + (size_t)j * 64))[i];
  float bias = b[j];
  int stride = gridDim.x * 4;
  for (int node = blockIdx.x * 4 + nl; node < n; node += stride) {
    float zv = z[(size_t)node * 64 + j];
    float acc = bias;
#pragma unroll
    for (int k = 0; k < 64; ++k)
      acc += __shfl(zv, k) * wreg[k];
    out[(size_t)node * 64 + j] = acc;
  }
}

extern "C" void kernel_launch(void* const* d_in, const int* in_sizes, int n_in,
                              void* d_out, int out_size, void* d_ws, size_t ws_size,
                              hipStream_t stream) {
  const float* h   = (const float*)d_in[0];
  const float* tax = (const float*)d_in[1];
  const int*   src = (const int*)d_in[2];
  const int*   dst = (const int*)d_in[3];
  const float* whw = (const float*)d_in[4];
  const float* Ww  = (const float*)d_in[5];
  const float* Wb  = (const float*)d_in[6];
  float* out = (float*)d_out;
  int n  = in_sizes[0] / 64;
  int ne = in_sizes[2];
  int nb = (n + 511) >> 9;  // coarse buckets (196 for n=100k); requires nb<=256

  // Workspace layout (4-byte elements):
  float* af   = (float*)d_ws;               // n
  float* bf   = af + n;                     // n
  int*   off  = (int*)(bf + n);             // n+1
  int*   srcs = off + n + 1;                // ne
  float* z    = (float*)(srcs + ne);        // n*64
  int*   gcur = (int*)(z + (size_t)n * 64); // 256
  int*   cbase = gcur + 256;                // 256
  // Pair planes alias z (consumed by k_finesort before k_fused writes z):
  int* psrc = (int*)z;                      // nb*CAP
  int* pdst = psrc + (size_t)nb * CAP;      // nb*CAP  (2*nb*CAP*4B <= n*256B)

  int bn16 = (n * 16 + 255) / 256;
  int bp   = (ne + PCHUNK - 1) / PCHUNK;
  int bw   = (int)(((size_t)n * 64 + 255) / 256);

  k_prep<<<bn16, 256, 0, stream>>>(h, whw, af, bf, gcur, n);
  k_partition<<<bp, 256, 0, stream>>>(src, dst, gcur, psrc, pdst, ne);
  k_cscan<<<1, 256, 0, stream>>>(gcur, cbase, off, nb, n, ne);
  k_finesort<<<nb, 256, 0, stream>>>(psrc, pdst, gcur, cbase, off, srcs, n);
  k_fused<<<bw, 256, 0, stream>>>(h, tax, af, bf, off, srcs, z, n);
  k_out_gemm<<<1024, 256, 0, stream>>>(z, Ww, Wb, out, n);
}

// Round 7
// 349.238 us; speedup vs baseline: 1.4041x; 1.0019x over previous
//
#include <hip/hip_runtime.h>

#define NEG_SLOPE 0.01f
#define ETA 0.5f
#define NEG_BIG -3.402823466e38f
#define PCHUNK 4096   // edges per k_partition block
#define CAP 10240     // per-coarse-bucket capacity (mean 8192 + 22 sigma)

__device__ __forceinline__ unsigned short bf16rne(float x) {
  unsigned u = __float_as_uint(x);
  return (unsigned short)((u + 0x7fffu + ((u >> 16) & 1u)) >> 16);
}

// Node dots af/bf + bf16 copies of h and tax rows + zero bucket cursors.
__global__ void k_prep(const float* __restrict__ h, const float* __restrict__ tax,
                       const float* __restrict__ whw,
                       float* __restrict__ af, float* __restrict__ bf,
                       unsigned short* __restrict__ hb, unsigned short* __restrict__ txb,
                       int* __restrict__ gcur, int n) {
  int gid = blockIdx.x * blockDim.x + threadIdx.x;
  if (gid < 256) gcur[gid] = 0;
  int node = gid >> 4, lane = gid & 15;
  if (node >= n) return;
  float4 x  = ((const float4*)(h + (size_t)node * 64))[lane];
  float4 tx = ((const float4*)(tax + (size_t)node * 64))[lane];
  float4 wa = ((const float4*)whw)[lane];
  float4 wb = ((const float4*)(whw + 64))[lane];
  ushort4 hq = make_ushort4(bf16rne(x.x), bf16rne(x.y), bf16rne(x.z), bf16rne(x.w));
  ushort4 tq = make_ushort4(bf16rne(tx.x), bf16rne(tx.y), bf16rne(tx.z), bf16rne(tx.w));
  ((ushort4*)(hb + (size_t)node * 64))[lane] = hq;
  ((ushort4*)(txb + (size_t)node * 64))[lane] = tq;
  float pa = x.x * wa.x + x.y * wa.y + x.z * wa.z + x.w * wa.w;
  float pb = x.x * wb.x + x.y * wb.y + x.z * wb.z + x.w * wb.w;
#pragma unroll
  for (int o = 8; o; o >>= 1) {
    pa += __shfl_xor(pa, o);
    pb += __shfl_xor(pb, o);
  }
  if (lane == 0) { af[node] = pa; bf[node] = pb; }
}

// Coarse partition by bucket = dst>>9. Two-pass: LDS hist -> one global
// atomic reservation per (block,bucket) -> direct scatter of packed
// (src<<9)|(dst&511) into per-bucket runs (write-amplification-free).
__global__ void k_partition(const int* __restrict__ src, const int* __restrict__ dst,
                            int* __restrict__ gcur, int* __restrict__ pck, int ne) {
  __shared__ int s_hist[256];
  __shared__ int s_res[256];
  __shared__ int s_cur[256];
  int t = threadIdx.x;
  int base = blockIdx.x * PCHUNK;
  int cnt = ne - base; if (cnt > PCHUNK) cnt = PCHUNK;
  s_hist[t] = 0;
  __syncthreads();
  for (int i = t; i < cnt; i += 256)
    atomicAdd(&s_hist[dst[base + i] >> 9], 1);
  __syncthreads();
  int v = s_hist[t];
  if (v > 0) s_res[t] = atomicAdd(&gcur[t], v);
  s_cur[t] = 0;
  __syncthreads();
  for (int i = t; i < cnt; i += 256) {
    int d = dst[base + i];
    int r = d >> 9;
    int g = s_res[r] + atomicAdd(&s_cur[r], 1);
    if (g < CAP)  // statistically impossible overflow guard
      pck[r * CAP + g] = (src[base + i] << 9) | (d & 511);
  }
}

// Exclusive scan of nb coarse-bucket counts -> CSR base per bucket.
__global__ void k_cscan(const int* __restrict__ gcur, int* __restrict__ cbase,
                        int* __restrict__ off, int nb, int n, int ne) {
  __shared__ int sh[256];
  int t = threadIdx.x;
  int v = (t < nb) ? gcur[t] : 0;
  sh[t] = v;
  __syncthreads();
  for (int s = 1; s < 256; s <<= 1) {
    int a = (t >= s) ? sh[t - s] : 0;
    __syncthreads();
    sh[t] += a;
    __syncthreads();
  }
  if (t < nb) cbase[t] = sh[t] - v;
  if (t == 0) off[n] = ne;
}

// One block per coarse bucket: LDS 512-dst histogram + scan -> exact off[],
// then scatter srcs into this bucket's contiguous CSR window.
__global__ void k_finesort(const int* __restrict__ pck,
                           const int* __restrict__ gcur, const int* __restrict__ cbase,
                           int* __restrict__ off, int* __restrict__ srcs, int n) {
  __shared__ int s_hist[512];
  __shared__ int s_scan[512];
  __shared__ int s_pair[256];
  int b = blockIdx.x;
  int t = threadIdx.x;
  int cnt = gcur[b];
  int gbase = b * CAP;
  int base = cbase[b];
  s_hist[t] = 0; s_hist[t + 256] = 0;
  __syncthreads();
  for (int i = t; i < cnt; i += 256)
    atomicAdd(&s_hist[pck[gbase + i] & 511], 1);
  __syncthreads();
  int c0 = s_hist[2 * t], c1 = s_hist[2 * t + 1];
  int v = c0 + c1;
  s_pair[t] = v;
  __syncthreads();
  for (int s = 1; s < 256; s <<= 1) {
    int a = (t >= s) ? s_pair[t - s] : 0;
    __syncthreads();
    s_pair[t] += a;
    __syncthreads();
  }
  int pex = s_pair[t] - v;
  s_scan[2 * t] = pex;
  s_scan[2 * t + 1] = pex + c0;
  __syncthreads();
  int d0 = (b << 9) + 2 * t;
  if (d0 < n) off[d0] = base + s_scan[2 * t];
  if (d0 + 1 < n) off[d0 + 1] = base + s_scan[2 * t + 1];
  s_hist[2 * t] = s_scan[2 * t];
  s_hist[2 * t + 1] = s_scan[2 * t + 1];
  __syncthreads();
  for (int i = t; i < cnt; i += 256) {
    int p = pck[gbase + i];
    int rank = atomicAdd(&s_hist[p & 511], 1);
    srcs[base + rank] = p >> 9;
  }
}

// One wave per dst node, 4 edges in flight (16 lanes x 4 features each).
// Gathered rows are bf16 (halved bytes); dst tax row stays fp32; all
// accumulation fp32. f-stream no-max softmax; t-stream online max.
__global__ void k_fused(const unsigned short* __restrict__ hb,
                        const unsigned short* __restrict__ txb,
                        const float* __restrict__ tax,
                        const float* __restrict__ af, const float* __restrict__ bf,
                        const int* __restrict__ off, const int* __restrict__ srcs,
                        float* __restrict__ z, int n) {
  int wave = (blockIdx.x * blockDim.x + threadIdx.x) >> 6;
  if (wave >= n) return;
  int lane = threadIdx.x & 63;
  int g = lane >> 4, q = lane & 15;
  int d = wave;
  int beg = off[d], end = off[d + 1];
  float4 td = ((const float4*)(tax + (size_t)d * 64))[q];
  float bfd = bf[d];
  float sf = 0.f;
  float4 zf = make_float4(0.f, 0.f, 0.f, 0.f);
  float mt = NEG_BIG, st = 0.f;
  float4 zt = make_float4(0.f, 0.f, 0.f, 0.f);
  for (int i = beg + g; i < end; i += 4) {
    int s = srcs[i];
    uint2 tu = ((const uint2*)(txb + ((size_t)s << 6)))[q];
    uint2 hu = ((const uint2*)(hb + ((size_t)s << 6)))[q];
    float tsx = __uint_as_float(tu.x << 16);
    float tsy = __uint_as_float(tu.x & 0xffff0000u);
    float tsz = __uint_as_float(tu.y << 16);
    float tsw = __uint_as_float(tu.y & 0xffff0000u);
    float hvx = __uint_as_float(hu.x << 16);
    float hvy = __uint_as_float(hu.x & 0xffff0000u);
    float hvz = __uint_as_float(hu.y << 16);
    float hvw = __uint_as_float(hu.y & 0xffff0000u);
    float p = tsx * td.x + tsy * td.y + tsz * td.z + tsw * td.w;
    p += __shfl_xor(p, 1);
    p += __shfl_xor(p, 2);
    p += __shfl_xor(p, 4);
    p += __shfl_xor(p, 8);
    float wf = af[s] + bfd;
    wf = (wf > 0.f) ? wf : NEG_SLOPE * wf;
    float ef = __expf(wf);
    sf += ef;
    zf.x += ef * hvx; zf.y += ef * hvy; zf.z += ef * hvz; zf.w += ef * hvw;
    float nm = fmaxf(mt, p);
    float sc = __expf(mt - nm);
    float et = __expf(p - nm);
    st = st * sc + et;
    zt.x = zt.x * sc + et * hvx;
    zt.y = zt.y * sc + et * hvy;
    zt.z = zt.z * sc + et * hvz;
    zt.w = zt.w * sc + et * hvw;
    mt = nm;
  }
#pragma unroll
  for (int o = 16; o < 64; o <<= 1) {
    sf += __shfl_xor(sf, o);
    zf.x += __shfl_xor(zf.x, o); zf.y += __shfl_xor(zf.y, o);
    zf.z += __shfl_xor(zf.z, o); zf.w += __shfl_xor(zf.w, o);
    float mo  = __shfl_xor(mt, o);
    float so  = __shfl_xor(st, o);
    float zox = __shfl_xor(zt.x, o), zoy = __shfl_xor(zt.y, o);
    float zoz = __shfl_xor(zt.z, o), zow = __shfl_xor(zt.w, o);
    float nm = fmaxf(mt, mo);
    float a = __expf(mt - nm);
    float b = __expf(mo - nm);
    st = st * a + so * b;
    zt.x = zt.x * a + zox * b;
    zt.y = zt.y * a + zoy * b;
    zt.z = zt.z * a + zoz * b;
    zt.w = zt.w * a + zow * b;
    mt = nm;
  }
  if (g == 0) {
    float4 zv = make_float4(0.f, 0.f, 0.f, 0.f);
    if (end > beg) {
      float rf = ETA / sf, rt = (1.f - ETA) / st;
      zv.x = rf * zf.x + rt * zt.x;
      zv.y = rf * zf.y + rt * zt.y;
      zv.z = rf * zf.z + rt * zt.z;
      zv.w = rf * zf.w + rt * zt.w;
    }
    ((float4*)(z + (size_t)d * 64))[q] = zv;
  }
}

// out[n][j] = sum_k z[n][k] * W[j][k] + b[j].
__launch_bounds__(256)
__global__ void k_out_gemm(const float* __restrict__ z, const float* __restrict__ W,
                           const float* __restrict__ b, float* __restrict__ out, int n) {
  int t = threadIdx.x;
  int j = t & 63, nl = t >> 6;
  float wreg[64];
#pragma unroll
  for (int i = 0; i < 16; ++i)
    ((float4*)wreg)[i] = ((const float4*)(W + (size_t)j * 64))[i];
  float bias = b[j];
  int stride = gridDim.x * 4;
  for (int node = blockIdx.x * 4 + nl; node < n; node += stride) {
    float zv = z[(size_t)node * 64 + j];
    float acc = bias;
#pragma unroll
    for (int k = 0; k < 64; ++k)
      acc += __shfl(zv, k) * wreg[k];
    out[(size_t)node * 64 + j] = acc;
  }
}

extern "C" void kernel_launch(void* const* d_in, const int* in_sizes, int n_in,
                              void* d_out, int out_size, void* d_ws, size_t ws_size,
                              hipStream_t stream) {
  const float* h   = (const float*)d_in[0];
  const float* tax = (const float*)d_in[1];
  const int*   src = (const int*)d_in[2];
  const int*   dst = (const int*)d_in[3];
  const float* whw = (const float*)d_in[4];
  const float* Ww  = (const float*)d_in[5];
  const float* Wb  = (const float*)d_in[6];
  float* out = (float*)d_out;
  int n  = in_sizes[0] / 64;
  int ne = in_sizes[2];
  int nb = (n + 511) >> 9;  // coarse buckets (196 for n=100k); nb<=256

  // Workspace layout (4-byte units unless noted):
  float* af   = (float*)d_ws;               // n
  float* bf   = af + n;                     // n
  int*   off  = (int*)(bf + n);             // n+1
  int*   srcs = off + n + 1;                // ne
  float* z    = (float*)(srcs + ne);        // n*64
  unsigned short* hb  = (unsigned short*)(z + (size_t)n * 64);  // n*64 u16
  unsigned short* txb = hb + (size_t)n * 64;                    // n*64 u16
  int*   gcur = (int*)(txb + (size_t)n * 64); // 256
  int*   cbase = gcur + 256;                  // 256
  // Packed sort plane aliases z (consumed by k_finesort before z written):
  int* pck = (int*)z;                         // nb*CAP <= n*64

  int bn16 = (n * 16 + 255) / 256;
  int bp   = (ne + PCHUNK - 1) / PCHUNK;
  int bw   = (int)(((size_t)n * 64 + 255) / 256);

  k_prep<<<bn16, 256, 0, stream>>>(h, tax, whw, af, bf, hb, txb, gcur, n);
  k_partition<<<bp, 256, 0, stream>>>(src, dst, gcur, pck, ne);
  k_cscan<<<1, 256, 0, stream>>>(gcur, cbase, off, nb, n, ne);
  k_finesort<<<nb, 256, 0, stream>>>(pck, gcur, cbase, off, srcs, n);
  k_fused<<<bw, 256, 0, stream>>>(hb, txb, tax, af, bf, off, srcs, z, n);
  k_out_gemm<<<1024, 256, 0, stream>>>(z, Ww, Wb, out, n);
}

// Round 8
// 340.617 us; speedup vs baseline: 1.4397x; 1.0253x over previous
//
#include <hip/hip_runtime.h>

#define NEG_SLOPE 0.01f
#define ETA 0.5f
#define NEG_BIG -3.402823466e38f
#define PCHUNK 4096   // edges per k_partition block
#define CAP 10240     // per-coarse-bucket capacity (mean 8192 + 22 sigma)

__device__ __forceinline__ unsigned short bf16rne(float x) {
  unsigned u = __float_as_uint(x);
  return (unsigned short)((u + 0x7fffu + ((u >> 16) & 1u)) >> 16);
}
__device__ __forceinline__ float bf16up(unsigned short s) {
  return __uint_as_float(((unsigned)s) << 16);
}

// Node dots af/bf + bf16 copies of h and tax rows + zero bucket cursors.
__global__ void k_prep(const float* __restrict__ h, const float* __restrict__ tax,
                       const float* __restrict__ whw,
                       float* __restrict__ af, float* __restrict__ bf,
                       unsigned short* __restrict__ hb, unsigned short* __restrict__ txb,
                       int* __restrict__ gcur, int n) {
  int gid = blockIdx.x * blockDim.x + threadIdx.x;
  if (gid < 256) gcur[gid] = 0;
  int node = gid >> 4, lane = gid & 15;
  if (node >= n) return;
  float4 x  = ((const float4*)(h + (size_t)node * 64))[lane];
  float4 tx = ((const float4*)(tax + (size_t)node * 64))[lane];
  float4 wa = ((const float4*)whw)[lane];
  float4 wb = ((const float4*)(whw + 64))[lane];
  ushort4 hq = make_ushort4(bf16rne(x.x), bf16rne(x.y), bf16rne(x.z), bf16rne(x.w));
  ushort4 tq = make_ushort4(bf16rne(tx.x), bf16rne(tx.y), bf16rne(tx.z), bf16rne(tx.w));
  ((ushort4*)(hb + (size_t)node * 64))[lane] = hq;
  ((ushort4*)(txb + (size_t)node * 64))[lane] = tq;
  float pa = x.x * wa.x + x.y * wa.y + x.z * wa.z + x.w * wa.w;
  float pb = x.x * wb.x + x.y * wb.y + x.z * wb.z + x.w * wb.w;
#pragma unroll
  for (int o = 8; o; o >>= 1) {
    pa += __shfl_xor(pa, o);
    pb += __shfl_xor(pb, o);
  }
  if (lane == 0) { af[node] = pa; bf[node] = pb; }
}

// Coarse partition by bucket = dst>>9: LDS hist -> one global atomic
// reservation per (block,bucket) -> scatter packed (src<<9)|(dst&511).
__global__ void k_partition(const int* __restrict__ src, const int* __restrict__ dst,
                            int* __restrict__ gcur, int* __restrict__ pck, int ne) {
  __shared__ int s_hist[256];
  __shared__ int s_res[256];
  __shared__ int s_cur[256];
  int t = threadIdx.x;
  int base = blockIdx.x * PCHUNK;
  int cnt = ne - base; if (cnt > PCHUNK) cnt = PCHUNK;
  s_hist[t] = 0;
  __syncthreads();
  for (int i = t; i < cnt; i += 256)
    atomicAdd(&s_hist[dst[base + i] >> 9], 1);
  __syncthreads();
  int v = s_hist[t];
  if (v > 0) s_res[t] = atomicAdd(&gcur[t], v);
  s_cur[t] = 0;
  __syncthreads();
  for (int i = t; i < cnt; i += 256) {
    int d = dst[base + i];
    int r = d >> 9;
    int g = s_res[r] + atomicAdd(&s_cur[r], 1);
    if (g < CAP)  // statistically impossible overflow guard
      pck[r * CAP + g] = (src[base + i] << 9) | (d & 511);
  }
}

// One block per coarse bucket: compute own CSR base (inline scan of gcur),
// LDS 512-dst histogram + scan -> exact off[], scatter srcs into the
// bucket's contiguous CSR window.
__global__ void k_finesort(const int* __restrict__ pck, const int* __restrict__ gcur,
                           int* __restrict__ off, int* __restrict__ srcs,
                           int n, int nb) {
  __shared__ int s_hist[512];
  __shared__ int s_scan[512];
  __shared__ int s_pair[256];
  __shared__ int s_red[256];
  int b = blockIdx.x;
  int t = threadIdx.x;
  int cnt = gcur[b];
  int gbase = b * CAP;
  // base = sum of gcur[0..b)
  s_red[t] = (t < b && t < nb) ? gcur[t] : 0;
  s_hist[t] = 0; s_hist[t + 256] = 0;
  __syncthreads();
  for (int s = 128; s; s >>= 1) {
    if (t < s) s_red[t] += s_red[t + s];
    __syncthreads();
  }
  int base = s_red[0];
  for (int i = t; i < cnt; i += 256)
    atomicAdd(&s_hist[pck[gbase + i] & 511], 1);
  __syncthreads();
  int c0 = s_hist[2 * t], c1 = s_hist[2 * t + 1];
  int v = c0 + c1;
  s_pair[t] = v;
  __syncthreads();
  for (int s = 1; s < 256; s <<= 1) {
    int a = (t >= s) ? s_pair[t - s] : 0;
    __syncthreads();
    s_pair[t] += a;
    __syncthreads();
  }
  int pex = s_pair[t] - v;
  s_scan[2 * t] = pex;
  s_scan[2 * t + 1] = pex + c0;
  __syncthreads();
  int d0 = (b << 9) + 2 * t;
  if (d0 < n) off[d0] = base + s_scan[2 * t];
  if (d0 + 1 < n) off[d0 + 1] = base + s_scan[2 * t + 1];
  if (b == nb - 1 && t == 0) off[n] = base + cnt;
  s_hist[2 * t] = s_scan[2 * t];
  s_hist[2 * t + 1] = s_scan[2 * t + 1];
  __syncthreads();
  for (int i = t; i < cnt; i += 256) {
    int p = pck[gbase + i];
    int rank = atomicAdd(&s_hist[p & 511], 1);
    srcs[base + rank] = p >> 9;
  }
}

// One wave per dst node, 4 edges in flight (16 lanes x 4 features each).
// Gathered rows bf16; dst tax row fp32; fp32 accumulation; bf16 z output.
// srcs prefetched one iteration ahead to pipeline the gather chain.
__global__ void k_fused(const unsigned short* __restrict__ hb,
                        const unsigned short* __restrict__ txb,
                        const float* __restrict__ tax,
                        const float* __restrict__ af, const float* __restrict__ bf,
                        const int* __restrict__ off, const int* __restrict__ srcs,
                        unsigned short* __restrict__ z, int n) {
  int wave = (blockIdx.x * blockDim.x + threadIdx.x) >> 6;
  if (wave >= n) return;
  int lane = threadIdx.x & 63;
  int g = lane >> 4, q = lane & 15;
  int d = wave;
  int beg = off[d], end = off[d + 1];
  float4 td = ((const float4*)(tax + (size_t)d * 64))[q];
  float bfd = bf[d];
  float sf = 0.f;
  float4 zf = make_float4(0.f, 0.f, 0.f, 0.f);
  float mt = NEG_BIG, st = 0.f;
  float4 zt = make_float4(0.f, 0.f, 0.f, 0.f);
  int i = beg + g;
  int sNext = (i < end) ? srcs[i] : 0;
  for (; i < end; i += 4) {
    int s = sNext;
    int i2 = i + 4;
    if (i2 < end) sNext = srcs[i2];
    uint2 tu = ((const uint2*)(txb + ((size_t)s << 6)))[q];
    uint2 hu = ((const uint2*)(hb + ((size_t)s << 6)))[q];
    float afs = af[s];
    float tsx = __uint_as_float(tu.x << 16);
    float tsy = __uint_as_float(tu.x & 0xffff0000u);
    float tsz = __uint_as_float(tu.y << 16);
    float tsw = __uint_as_float(tu.y & 0xffff0000u);
    float hvx = __uint_as_float(hu.x << 16);
    float hvy = __uint_as_float(hu.x & 0xffff0000u);
    float hvz = __uint_as_float(hu.y << 16);
    float hvw = __uint_as_float(hu.y & 0xffff0000u);
    float p = tsx * td.x + tsy * td.y + tsz * td.z + tsw * td.w;
    p += __shfl_xor(p, 1);
    p += __shfl_xor(p, 2);
    p += __shfl_xor(p, 4);
    p += __shfl_xor(p, 8);
    float wf = afs + bfd;
    wf = (wf > 0.f) ? wf : NEG_SLOPE * wf;
    float ef = __expf(wf);
    sf += ef;
    zf.x += ef * hvx; zf.y += ef * hvy; zf.z += ef * hvz; zf.w += ef * hvw;
    float nm = fmaxf(mt, p);
    float sc = __expf(mt - nm);
    float et = __expf(p - nm);
    st = st * sc + et;
    zt.x = zt.x * sc + et * hvx;
    zt.y = zt.y * sc + et * hvy;
    zt.z = zt.z * sc + et * hvz;
    zt.w = zt.w * sc + et * hvw;
    mt = nm;
  }
#pragma unroll
  for (int o = 16; o < 64; o <<= 1) {
    sf += __shfl_xor(sf, o);
    zf.x += __shfl_xor(zf.x, o); zf.y += __shfl_xor(zf.y, o);
    zf.z += __shfl_xor(zf.z, o); zf.w += __shfl_xor(zf.w, o);
    float mo  = __shfl_xor(mt, o);
    float so  = __shfl_xor(st, o);
    float zox = __shfl_xor(zt.x, o), zoy = __shfl_xor(zt.y, o);
    float zoz = __shfl_xor(zt.z, o), zow = __shfl_xor(zt.w, o);
    float nm = fmaxf(mt, mo);
    float a = __expf(mt - nm);
    float b = __expf(mo - nm);
    st = st * a + so * b;
    zt.x = zt.x * a + zox * b;
    zt.y = zt.y * a + zoy * b;
    zt.z = zt.z * a + zoz * b;
    zt.w = zt.w * a + zow * b;
    mt = nm;
  }
  if (g == 0) {
    float4 zv = make_float4(0.f, 0.f, 0.f, 0.f);
    if (end > beg) {
      float rf = ETA / sf, rt = (1.f - ETA) / st;
      zv.x = rf * zf.x + rt * zt.x;
      zv.y = rf * zf.y + rt * zt.y;
      zv.z = rf * zf.z + rt * zt.z;
      zv.w = rf * zf.w + rt * zt.w;
    }
    ((ushort4*)(z + (size_t)d * 64))[q] =
        make_ushort4(bf16rne(zv.x), bf16rne(zv.y), bf16rne(zv.z), bf16rne(zv.w));
  }
}

// out[n][j] = sum_k z[n][k] * W[j][k] + b[j], z in bf16.
__launch_bounds__(256)
__global__ void k_out_gemm(const unsigned short* __restrict__ z,
                           const float* __restrict__ W,
                           const float* __restrict__ b, float* __restrict__ out, int n) {
  int t = threadIdx.x;
  int j = t & 63, nl = t >> 6;
  float wreg[64];
#pragma unroll
  for (int i = 0; i < 16; ++i)
    ((float4*)wreg)[i] = ((const float4*)(W + (size_t)j * 64))[i];
  float bias = b[j];
  int stride = gridDim.x * 4;
  for (int node = blockIdx.x * 4 + nl; node < n; node += stride) {
    float zv = bf16up(z[(size_t)node * 64 + j]);
    float acc = bias;
#pragma unroll
    for (int k = 0; k < 64; ++k)
      acc += __shfl(zv, k) * wreg[k];
    out[(size_t)node * 64 + j] = acc;
  }
}

extern "C" void kernel_launch(void* const* d_in, const int* in_sizes, int n_in,
                              void* d_out, int out_size, void* d_ws, size_t ws_size,
                              hipStream_t stream) {
  const float* h   = (const float*)d_in[0];
  const float* tax = (const float*)d_in[1];
  const int*   src = (const int*)d_in[2];
  const int*   dst = (const int*)d_in[3];
  const float* whw = (const float*)d_in[4];
  const float* Ww  = (const float*)d_in[5];
  const float* Wb  = (const float*)d_in[6];
  float* out = (float*)d_out;
  int n  = in_sizes[0] / 64;
  int ne = in_sizes[2];
  int nb = (n + 511) >> 9;  // coarse buckets (196 for n=100k); nb<=256

  // Workspace layout (4-byte units unless noted; off padded to n+2 so the
  // u16 planes start 8-byte aligned):
  float* af   = (float*)d_ws;               // n
  float* bf   = af + n;                     // n
  int*   off  = (int*)(bf + n);             // n+2
  int*   srcs = off + n + 2;                // ne
  unsigned short* z   = (unsigned short*)(srcs + ne);  // n*64 u16
  unsigned short* hb  = z + (size_t)n * 64;            // n*64 u16
  unsigned short* txb = hb + (size_t)n * 64;           // n*64 u16
  int*   gcur = (int*)(txb + (size_t)n * 64); // 256
  // Packed sort plane aliases z (consumed by k_finesort before z written):
  int* pck = (int*)z;                         // nb*CAP*4B <= n*64*2B*? (8MB<=12.8MB)

  int bn16 = (n * 16 + 255) / 256;
  int bp   = (ne + PCHUNK - 1) / PCHUNK;
  int bw   = (int)(((size_t)n * 64 + 255) / 256);

  k_prep<<<bn16, 256, 0, stream>>>(h, tax, whw, af, bf, hb, txb, gcur, n);
  k_partition<<<bp, 256, 0, stream>>>(src, dst, gcur, pck, ne);
  k_finesort<<<nb, 256, 0, stream>>>(pck, gcur, off, srcs, n, nb);
  k_fused<<<bw, 256, 0, stream>>>(hb, txb, tax, af, bf, off, srcs, z, n);
  k_out_gemm<<<1024, 256, 0, stream>>>(z, Ww, Wb, out, n);
}

// Round 9
// 318.233 us; speedup vs baseline: 1.5409x; 1.0703x over previous
//
#include <hip/hip_runtime.h>

#define NEG_SLOPE 0.01f
#define ETA 0.5f
#define NEG_BIG -3.402823466e38f
#define PCHUNK 4096   // edges per k_partition block
#define CAP 10240     // per-coarse-bucket capacity (mean 8192 + 22 sigma)

typedef _Float16 half2v __attribute__((ext_vector_type(2)));

#if defined(__has_builtin)
#if __has_builtin(__builtin_amdgcn_fdot2)
#define HAVE_FDOT2 1
#endif
#endif

__device__ __forceinline__ float fdot2(half2v a, half2v b, float c) {
#ifdef HAVE_FDOT2
  return __builtin_amdgcn_fdot2(a, b, c, false);
#else
  return (float)a[0] * (float)b[0] + (float)a[1] * (float)b[1] + c;
#endif
}

__device__ __forceinline__ unsigned pack2(float x, float y) {
  half2v h = {( _Float16)x, (_Float16)y};
  return __builtin_bit_cast(unsigned, h);
}

// Node dots af/bf + interleaved f16 record [tax4|h4] per 16B chunk + zero cursors.
__global__ void k_prep(const float* __restrict__ h, const float* __restrict__ tax,
                       const float* __restrict__ whw,
                       float* __restrict__ af, float* __restrict__ bf,
                       uint4* __restrict__ rec, int* __restrict__ gcur, int n) {
  int gid = blockIdx.x * blockDim.x + threadIdx.x;
  if (gid < 256) gcur[gid] = 0;
  int node = gid >> 4, lane = gid & 15;
  if (node >= n) return;
  float4 x  = ((const float4*)(h + (size_t)node * 64))[lane];
  float4 tx = ((const float4*)(tax + (size_t)node * 64))[lane];
  float4 wa = ((const float4*)whw)[lane];
  float4 wb = ((const float4*)(whw + 64))[lane];
  uint4 r;
  r.x = pack2(tx.x, tx.y);
  r.y = pack2(tx.z, tx.w);
  r.z = pack2(x.x, x.y);
  r.w = pack2(x.z, x.w);
  rec[((size_t)node << 4) + lane] = r;
  float pa = x.x * wa.x + x.y * wa.y + x.z * wa.z + x.w * wa.w;
  float pb = x.x * wb.x + x.y * wb.y + x.z * wb.z + x.w * wb.w;
#pragma unroll
  for (int o = 8; o; o >>= 1) {
    pa += __shfl_xor(pa, o);
    pb += __shfl_xor(pb, o);
  }
  if (lane == 0) { af[node] = pa; bf[node] = pb; }
}

// Coarse partition by bucket = dst>>9: LDS hist -> one global atomic
// reservation per (block,bucket) -> scatter packed (src<<9)|(dst&511).
__global__ void k_partition(const int* __restrict__ src, const int* __restrict__ dst,
                            int* __restrict__ gcur, int* __restrict__ pck, int ne) {
  __shared__ int s_hist[256];
  __shared__ int s_res[256];
  __shared__ int s_cur[256];
  int t = threadIdx.x;
  int base = blockIdx.x * PCHUNK;
  int cnt = ne - base; if (cnt > PCHUNK) cnt = PCHUNK;
  s_hist[t] = 0;
  __syncthreads();
  for (int i = t; i < cnt; i += 256)
    atomicAdd(&s_hist[dst[base + i] >> 9], 1);
  __syncthreads();
  int v = s_hist[t];
  if (v > 0) s_res[t] = atomicAdd(&gcur[t], v);
  s_cur[t] = 0;
  __syncthreads();
  for (int i = t; i < cnt; i += 256) {
    int d = dst[base + i];
    int r = d >> 9;
    int g = s_res[r] + atomicAdd(&s_cur[r], 1);
    if (g < CAP)  // statistically impossible overflow guard
      pck[r * CAP + g] = (src[base + i] << 9) | (d & 511);
  }
}

// One block per coarse bucket: compute own CSR base (inline reduce of gcur),
// LDS 512-dst histogram + scan -> exact off[], scatter srcs into window.
__global__ void k_finesort(const int* __restrict__ pck, const int* __restrict__ gcur,
                           int* __restrict__ off, int* __restrict__ srcs,
                           int n, int nb) {
  __shared__ int s_hist[512];
  __shared__ int s_scan[512];
  __shared__ int s_pair[256];
  __shared__ int s_red[256];
  int b = blockIdx.x;
  int t = threadIdx.x;
  int cnt = gcur[b];
  int gbase = b * CAP;
  s_red[t] = (t < b && t < nb) ? gcur[t] : 0;
  s_hist[t] = 0; s_hist[t + 256] = 0;
  __syncthreads();
  for (int s = 128; s; s >>= 1) {
    if (t < s) s_red[t] += s_red[t + s];
    __syncthreads();
  }
  int base = s_red[0];
  for (int i = t; i < cnt; i += 256)
    atomicAdd(&s_hist[pck[gbase + i] & 511], 1);
  __syncthreads();
  int c0 = s_hist[2 * t], c1 = s_hist[2 * t + 1];
  int v = c0 + c1;
  s_pair[t] = v;
  __syncthreads();
  for (int s = 1; s < 256; s <<= 1) {
    int a = (t >= s) ? s_pair[t - s] : 0;
    __syncthreads();
    s_pair[t] += a;
    __syncthreads();
  }
  int pex = s_pair[t] - v;
  s_scan[2 * t] = pex;
  s_scan[2 * t + 1] = pex + c0;
  __syncthreads();
  int d0 = (b << 9) + 2 * t;
  if (d0 < n) off[d0] = base + s_scan[2 * t];
  if (d0 + 1 < n) off[d0 + 1] = base + s_scan[2 * t + 1];
  if (b == nb - 1 && t == 0) off[n] = base + cnt;
  s_hist[2 * t] = s_scan[2 * t];
  s_hist[2 * t + 1] = s_scan[2 * t + 1];
  __syncthreads();
  for (int i = t; i < cnt; i += 256) {
    int p = pck[gbase + i];
    int rank = atomicAdd(&s_hist[p & 511], 1);
    srcs[base + rank] = p >> 9;
  }
}

// One wave per dst node, 4 edges in flight (16 lanes x 4 features each).
// Per edge: ONE uint4 load (interleaved f16 tax|h record), fdot2 t-dot,
// no-max f-softmax, deferred-rescale t-softmax (branch ~once per node).
__global__ void k_fused(const uint4* __restrict__ rec,
                        const float* __restrict__ af, const float* __restrict__ bf,
                        const int* __restrict__ off, const int* __restrict__ srcs,
                        unsigned short* __restrict__ z, int n) {
  int wave = (blockIdx.x * blockDim.x + threadIdx.x) >> 6;
  if (wave >= n) return;
  int lane = threadIdx.x & 63;
  int g = lane >> 4, q = lane & 15;
  int d = wave;
  int beg = off[d], end = off[d + 1];
  uint4 rd = rec[((size_t)d << 4) + q];
  half2v d01 = __builtin_bit_cast(half2v, rd.x);
  half2v d23 = __builtin_bit_cast(half2v, rd.y);
  float bfd = bf[d];
  float sf = 0.f;
  float4 zf = make_float4(0.f, 0.f, 0.f, 0.f);
  float mt = NEG_BIG, st = 0.f;
  float4 zt = make_float4(0.f, 0.f, 0.f, 0.f);
  int i = beg + g;
  int sNext = (i < end) ? srcs[i] : 0;
  for (; i < end; i += 4) {
    int s = sNext;
    if (i + 4 < end) sNext = srcs[i + 4];
    uint4 r = rec[((size_t)s << 4) + q];
    float afs = af[s];
    half2v t01 = __builtin_bit_cast(half2v, r.x);
    half2v t23 = __builtin_bit_cast(half2v, r.y);
    half2v h01 = __builtin_bit_cast(half2v, r.z);
    half2v h23 = __builtin_bit_cast(half2v, r.w);
    float p = fdot2(t23, d23, fdot2(t01, d01, 0.f));
    p += __shfl_xor(p, 1);
    p += __shfl_xor(p, 2);
    p += __shfl_xor(p, 4);
    p += __shfl_xor(p, 8);
    float hvx = (float)h01[0], hvy = (float)h01[1];
    float hvz = (float)h23[0], hvw = (float)h23[1];
    float wf = afs + bfd;
    wf = (wf > 0.f) ? wf : NEG_SLOPE * wf;
    float ef = __expf(wf);
    sf += ef;
    zf.x += ef * hvx; zf.y += ef * hvy; zf.z += ef * hvz; zf.w += ef * hvw;
    float pm = p - mt;
    if (pm > 60.f) {           // rare: first edge and new-max-by-far
      float sc = __expf(-pm);  // exp(mt - p); ==0 when mt==NEG_BIG
      st *= sc;
      zt.x *= sc; zt.y *= sc; zt.z *= sc; zt.w *= sc;
      mt = p; pm = 0.f;
    }
    float et = __expf(pm);
    st += et;
    zt.x += et * hvx; zt.y += et * hvy; zt.z += et * hvz; zt.w += et * hvw;
  }
  // Merge the 4 edge-groups (butterfly over group bits).
#pragma unroll
  for (int o = 16; o < 64; o <<= 1) {
    sf += __shfl_xor(sf, o);
    zf.x += __shfl_xor(zf.x, o); zf.y += __shfl_xor(zf.y, o);
    zf.z += __shfl_xor(zf.z, o); zf.w += __shfl_xor(zf.w, o);
    float mo  = __shfl_xor(mt, o);
    float so  = __shfl_xor(st, o);
    float zox = __shfl_xor(zt.x, o), zoy = __shfl_xor(zt.y, o);
    float zoz = __shfl_xor(zt.z, o), zow = __shfl_xor(zt.w, o);
    float nm = fmaxf(mt, mo);
    float a = __expf(mt - nm);
    float b = __expf(mo - nm);
    st = st * a + so * b;
    zt.x = zt.x * a + zox * b;
    zt.y = zt.y * a + zoy * b;
    zt.z = zt.z * a + zoz * b;
    zt.w = zt.w * a + zow * b;
    mt = nm;
  }
  if (g == 0) {
    float4 zv = make_float4(0.f, 0.f, 0.f, 0.f);
    if (end > beg) {
      float rf = ETA / sf, rt = (1.f - ETA) / st;
      zv.x = rf * zf.x + rt * zt.x;
      zv.y = rf * zf.y + rt * zt.y;
      zv.z = rf * zf.z + rt * zt.z;
      zv.w = rf * zf.w + rt * zt.w;
    }
    uint2 zo;
    zo.x = pack2(zv.x, zv.y);
    zo.y = pack2(zv.z, zv.w);
    ((uint2*)(z + (size_t)d * 64))[q] = zo;
  }
}

// out[n][j] = sum_k z[n][k] * W[j][k] + b[j], z in f16.
__launch_bounds__(256)
__global__ void k_out_gemm(const unsigned short* __restrict__ z,
                           const float* __restrict__ W,
                           const float* __restrict__ b, float* __restrict__ out, int n) {
  int t = threadIdx.x;
  int j = t & 63, nl = t >> 6;
  float wreg[64];
#pragma unroll
  for (int i = 0; i < 16; ++i)
    ((float4*)wreg)[i] = ((const float4*)(W + (size_t)j * 64))[i];
  float bias = b[j];
  int stride = gridDim.x * 4;
  for (int node = blockIdx.x * 4 + nl; node < n; node += stride) {
    float zv = (float)__builtin_bit_cast(_Float16, z[(size_t)node * 64 + j]);
    float acc = bias;
#pragma unroll
    for (int k = 0; k < 64; ++k)
      acc += __shfl(zv, k) * wreg[k];
    out[(size_t)node * 64 + j] = acc;
  }
}

extern "C" void kernel_launch(void* const* d_in, const int* in_sizes, int n_in,
                              void* d_out, int out_size, void* d_ws, size_t ws_size,
                              hipStream_t stream) {
  const float* h   = (const float*)d_in[0];
  const float* tax = (const float*)d_in[1];
  const int*   src = (const int*)d_in[2];
  const int*   dst = (const int*)d_in[3];
  const float* whw = (const float*)d_in[4];
  const float* Ww  = (const float*)d_in[5];
  const float* Wb  = (const float*)d_in[6];
  float* out = (float*)d_out;
  int n  = in_sizes[0] / 64;
  int ne = in_sizes[2];
  int nb = (n + 511) >> 9;  // coarse buckets (196 for n=100k); nb<=256

  // Workspace layout (4-byte words; rec aligned to 16 B):
  float* af   = (float*)d_ws;               // n
  float* bf   = af + n;                     // n
  int*   off  = (int*)(bf + n);             // n+2
  int*   srcs = off + n + 2;                // ne
  int*   gcur = srcs + ne;                  // 256
  size_t w = (size_t)(2 * n) + (n + 2) + ne + 256;
  w = (w + 3) & ~(size_t)3;                 // 16B-align
  unsigned short* z = (unsigned short*)((int*)d_ws + w);  // n*64 u16
  uint4* rec = (uint4*)(z + (size_t)n * 64);              // n*16 uint4
  // Packed sort plane aliases z (consumed by k_finesort before z written):
  int* pck = (int*)z;                       // nb*CAP*4B (8MB) <= n*128B (12.8MB)

  int bn16 = (n * 16 + 255) / 256;
  int bp   = (ne + PCHUNK - 1) / PCHUNK;
  int bw   = (int)(((size_t)n * 64 + 255) / 256);

  k_prep<<<bn16, 256, 0, stream>>>(h, tax, whw, af, bf, rec, gcur, n);
  k_partition<<<bp, 256, 0, stream>>>(src, dst, gcur, pck, ne);
  k_finesort<<<nb, 256, 0, stream>>>(pck, gcur, off, srcs, n, nb);
  k_fused<<<bw, 256, 0, stream>>>(rec, af, bf, off, srcs, z, n);
  k_out_gemm<<<1024, 256, 0, stream>>>(z, Ww, Wb, out, n);
}